// Round 1
// baseline (431.987 us; speedup 1.0000x reference)
//
#include <hip/hip_runtime.h>
#include <hip/hip_bf16.h>
#include <math.h>

#define IN_D 128
#define HID_D 128
#define OUT_D 64

typedef __attribute__((ext_vector_type(8))) short bf16x8;
typedef __attribute__((ext_vector_type(4))) float f32x4;

__device__ __forceinline__ unsigned short f2bf(float f) {
    unsigned u = __float_as_uint(f);
    u += 0x7fffu + ((u >> 16) & 1u);   // RTNE
    return (unsigned short)(u >> 16);
}
__device__ __forceinline__ float bf2f(unsigned short h) {
    return __uint_as_float(((unsigned)h) << 16);
}

// ---- fp32 -> bf16 convert (vectorized, n4 = n/4) ----
__global__ __launch_bounds__(256) void k_cvt(const float* __restrict__ src,
                                             unsigned short* __restrict__ dst, int n4) {
    int i = blockIdx.x * 256 + threadIdx.x;
    if (i < n4) {
        float4 v = ((const float4*)src)[i];
        ushort4 o;
        o.x = f2bf(v.x); o.y = f2bf(v.y); o.z = f2bf(v.z); o.w = f2bf(v.w);
        ((ushort4*)dst)[i] = o;
    }
}

// ---- concat two fp32 arrays -> bf16 (for [W;F] stacking) ----
__global__ __launch_bounds__(256) void k_concat(const float* __restrict__ a, int na,
                                                const float* __restrict__ b, int n,
                                                unsigned short* __restrict__ dst) {
    int i = blockIdx.x * 256 + threadIdx.x;
    if (i < n) dst[i] = f2bf(i < na ? a[i] : b[i - na]);
}

// ---- CSR build: count, scan, fill ----
__global__ __launch_bounds__(256) void k_count(const int* __restrict__ dst_idx,
                                               int* __restrict__ deg, int E) {
    int e = blockIdx.x * 256 + threadIdx.x;
    if (e < E) atomicAdd(&deg[dst_idx[e]], 1);
}

__global__ __launch_bounds__(1024) void k_scan(const int* __restrict__ deg,
                                               int* __restrict__ offs,
                                               int* __restrict__ cursor, int n) {
    __shared__ int wsum[16];
    __shared__ int woff[16];
    __shared__ int carry_s;
    __shared__ int total_s;
    int tid = threadIdx.x, lane = tid & 63, w = tid >> 6;
    if (tid == 0) carry_s = 0;
    __syncthreads();
    for (int base = 0; base < n; base += 1024) {
        int i = base + tid;
        int v = (i < n) ? deg[i] : 0;
        int x = v;
        #pragma unroll
        for (int d = 1; d < 64; d <<= 1) {
            int y = __shfl_up(x, d);
            if (lane >= d) x += y;
        }
        if (lane == 63) wsum[w] = x;
        __syncthreads();
        if (tid == 0) {
            int run = carry_s;
            #pragma unroll
            for (int k = 0; k < 16; k++) { int t = wsum[k]; woff[k] = run; run += t; }
            total_s = run;
        }
        __syncthreads();
        int excl = woff[w] + x - v;
        if (i < n) { offs[i] = excl; cursor[i] = excl; }
        if (tid == 0) carry_s = total_s;
        __syncthreads();
    }
    if (tid == 0) offs[n] = carry_s;
}

__global__ __launch_bounds__(256) void k_fill(const int* __restrict__ src_idx,
                                              const int* __restrict__ dst_idx,
                                              int* __restrict__ cursor,
                                              int* __restrict__ elist, int E) {
    int e = blockIdx.x * 256 + threadIdx.x;
    if (e < E) {
        int pos = atomicAdd(&cursor[dst_idx[e]], 1);
        elist[pos] = src_idx[e];
    }
}

// ---- fused GEMM + FiLM: Msg = relu(gamma * m + beta), all from one x @ Wc^T ----
// Wc is [W(128); Fgamma(128); Fbeta(128)] x 128, bf16 row-major.
// Block = 256 thr (4 waves), 16 rows/block. Wave w owns m col-tiles {2w, 2w+1}.
__global__ __launch_bounds__(256) void k_msg(const unsigned short* __restrict__ X,
                                             const unsigned short* __restrict__ Wc,
                                             unsigned short* __restrict__ Msg) {
    const int row0 = blockIdx.x << 4;
    const int wave = threadIdx.x >> 6;
    const int lane = threadIdx.x & 63;
    const int lr = lane & 15;
    const int quad = lane >> 4;

    const unsigned short* xp = X + (size_t)(row0 + lr) * IN_D + quad * 8;
    bf16x8 a[4];
    #pragma unroll
    for (int s = 0; s < 4; s++) a[s] = *(const bf16x8*)(xp + 32 * s);

    const int t0 = wave * 2;
    const int tidx[6] = {t0, t0 + 1, t0 + 8, t0 + 9, t0 + 16, t0 + 17};
    f32x4 acc[6];
    #pragma unroll
    for (int u = 0; u < 6; u++) acc[u] = (f32x4){0.f, 0.f, 0.f, 0.f};

    #pragma unroll
    for (int s = 0; s < 4; s++) {
        #pragma unroll
        for (int u = 0; u < 6; u++) {
            const bf16x8 b = *(const bf16x8*)(Wc + (size_t)(16 * tidx[u] + lr) * IN_D + quad * 8 + 32 * s);
            acc[u] = __builtin_amdgcn_mfma_f32_16x16x32_bf16(a[s], b, acc[u], 0, 0, 0);
        }
    }
    // FiLM epilogue: m=acc[0..1], gamma=acc[2..3], beta=acc[4..5]; same (row,col) slots.
    #pragma unroll
    for (int u = 0; u < 2; u++) {
        #pragma unroll
        for (int r = 0; r < 4; r++) {
            float v = acc[2 + u][r] * acc[u][r] + acc[4 + u][r];
            v = v > 0.f ? v : 0.f;
            Msg[(size_t)(row0 + quad * 4 + r) * HID_D + 16 * (t0 + u) + lr] = f2bf(v);
        }
    }
}

// ---- CSR aggregate + fused LayerNorm. One wave per dst node. ----
__global__ __launch_bounds__(256) void k_agg_ln(const unsigned short* __restrict__ Msg,
                                                const int* __restrict__ elist,
                                                const int* __restrict__ offs,
                                                const float* __restrict__ gamma,
                                                const float* __restrict__ beta,
                                                unsigned short* __restrict__ Hout, int n) {
    int node = blockIdx.x * 4 + (threadIdx.x >> 6);
    int lane = threadIdx.x & 63;
    if (node >= n) return;
    int s0 = offs[node], s1 = offs[node + 1];
    float a0 = 0.f, a1 = 0.f;
    for (int i = s0; i < s1; i++) {
        int sidx = elist[i];
        unsigned v = *(const unsigned*)(Msg + (size_t)sidx * HID_D + 2 * lane);
        a0 += bf2f((unsigned short)(v & 0xffffu));
        a1 += bf2f((unsigned short)(v >> 16));
    }
    float s = a0 + a1;
    float sq = a0 * a0 + a1 * a1;
    #pragma unroll
    for (int d = 32; d; d >>= 1) {
        s += __shfl_xor(s, d);
        sq += __shfl_xor(sq, d);
    }
    float mu = s * (1.f / 128.f);
    float var = sq * (1.f / 128.f) - mu * mu;
    float rs = rsqrtf(var + 1e-5f);
    int c = 2 * lane;
    float y0 = (a0 - mu) * rs * gamma[c] + beta[c];
    float y1 = (a1 - mu) * rs * gamma[c + 1] + beta[c + 1];
    unsigned o = (unsigned)f2bf(y0) | ((unsigned)f2bf(y1) << 16);
    *(unsigned*)(Hout + (size_t)node * HID_D + c) = o;
}

// ---- projection: out = sigmoid(h @ Wp^T + bp), OUT=64 -> wave w = col-tile w ----
__global__ __launch_bounds__(256) void k_proj(const unsigned short* __restrict__ H,
                                              const unsigned short* __restrict__ Wpb,
                                              const float* __restrict__ bp,
                                              float* __restrict__ out) {
    const int row0 = blockIdx.x << 4;
    const int wave = threadIdx.x >> 6;
    const int lane = threadIdx.x & 63;
    const int lr = lane & 15;
    const int quad = lane >> 4;
    const unsigned short* hp = H + (size_t)(row0 + lr) * HID_D + quad * 8;
    f32x4 acc = (f32x4){0.f, 0.f, 0.f, 0.f};
    #pragma unroll
    for (int s = 0; s < 4; s++) {
        bf16x8 av = *(const bf16x8*)(hp + 32 * s);
        bf16x8 bv = *(const bf16x8*)(Wpb + (size_t)(16 * wave + lr) * HID_D + quad * 8 + 32 * s);
        acc = __builtin_amdgcn_mfma_f32_16x16x32_bf16(av, bv, acc, 0, 0, 0);
    }
    float bias = bp[16 * wave + lr];
    #pragma unroll
    for (int r = 0; r < 4; r++) {
        float z = acc[r] + bias;
        out[(size_t)(row0 + quad * 4 + r) * OUT_D + 16 * wave + lr] = 1.f / (1.f + __expf(-z));
    }
}

extern "C" void kernel_launch(void* const* d_in, const int* in_sizes, int n_in,
                              void* d_out, int out_size, void* d_ws, size_t ws_size,
                              hipStream_t stream) {
    const float* features = (const float*)d_in[0];
    const int* src = (const int*)d_in[1];
    const int* dst = (const int*)d_in[2];
    const float* W1 = (const float*)d_in[3];
    const float* F1 = (const float*)d_in[4];
    const float* g1 = (const float*)d_in[5];
    const float* b1 = (const float*)d_in[6];
    const float* W2 = (const float*)d_in[7];
    const float* F2 = (const float*)d_in[8];
    const float* g2 = (const float*)d_in[9];
    const float* b2 = (const float*)d_in[10];
    const float* Wp = (const float*)d_in[11];
    const float* bp = (const float*)d_in[12];

    const int N = in_sizes[0] / IN_D;   // 50000
    const int E = in_sizes[1];          // 600000
    float* out = (float*)d_out;

    // workspace carve-up (256B aligned)
    char* p = (char*)d_ws;
    auto alloc = [&](size_t b) -> char* {
        char* r = p;
        p += (b + 255) & ~(size_t)255;
        return r;
    };
    unsigned short* buf0 = (unsigned short*)alloc((size_t)N * HID_D * 2);
    unsigned short* buf1 = (unsigned short*)alloc((size_t)N * HID_D * 2);
    unsigned short* wc1  = (unsigned short*)alloc((size_t)3 * HID_D * IN_D * 2);
    unsigned short* wc2  = (unsigned short*)alloc((size_t)3 * HID_D * HID_D * 2);
    unsigned short* wpb  = (unsigned short*)alloc((size_t)OUT_D * HID_D * 2);
    int* deg    = (int*)alloc((size_t)N * 4);
    int* cursor = (int*)alloc((size_t)N * 4);
    int* offs   = (int*)alloc((size_t)(N + 1) * 4);
    int* elist  = (int*)alloc((size_t)E * 4);

    const int eb = (E + 255) / 256;

    // CSR build (graph shared by both layers)
    hipMemsetAsync(deg, 0, (size_t)N * 4, stream);
    k_count<<<eb, 256, 0, stream>>>(dst, deg, E);
    k_scan<<<1, 1024, 0, stream>>>(deg, offs, cursor, N);
    k_fill<<<eb, 256, 0, stream>>>(src, dst, cursor, elist, E);

    // dtype prep
    k_cvt<<<(N * IN_D / 4 + 255) / 256, 256, 0, stream>>>(features, buf0, N * IN_D / 4);
    k_concat<<<(3 * HID_D * IN_D + 255) / 256, 256, 0, stream>>>(W1, HID_D * IN_D, F1, 3 * HID_D * IN_D, wc1);
    k_concat<<<(3 * HID_D * HID_D + 255) / 256, 256, 0, stream>>>(W2, HID_D * HID_D, F2, 3 * HID_D * HID_D, wc2);
    k_concat<<<(OUT_D * HID_D + 255) / 256, 256, 0, stream>>>(Wp, OUT_D * HID_D, nullptr, OUT_D * HID_D, wpb);

    // layer 1
    k_msg<<<N / 16, 256, 0, stream>>>(buf0, wc1, buf1);
    k_agg_ln<<<(N + 3) / 4, 256, 0, stream>>>(buf1, elist, offs, g1, b1, buf0, N);
    // layer 2
    k_msg<<<N / 16, 256, 0, stream>>>(buf0, wc2, buf1);
    k_agg_ln<<<(N + 3) / 4, 256, 0, stream>>>(buf1, elist, offs, g2, b2, buf0, N);
    // projection + sigmoid
    k_proj<<<N / 16, 256, 0, stream>>>(buf0, wpb, bp, out);
}

// Round 2
// 295.556 us; speedup vs baseline: 1.4616x; 1.4616x over previous
//
#include <hip/hip_runtime.h>
#include <hip/hip_bf16.h>
#include <math.h>

#define IN_D 128
#define HID_D 128
#define OUT_D 64

typedef __attribute__((ext_vector_type(8))) short bf16x8;
typedef __attribute__((ext_vector_type(4))) float f32x4;

__device__ __forceinline__ unsigned short f2bf(float f) {
    unsigned u = __float_as_uint(f);
    u += 0x7fffu + ((u >> 16) & 1u);   // RTNE
    return (unsigned short)(u >> 16);
}
__device__ __forceinline__ float bf2f(unsigned short h) {
    return __uint_as_float(((unsigned)h) << 16);
}

// ---- weight prep: [W1;F1]->wc1, [W2;F2]->wc2, Wp->wpb, all fp32->bf16 ----
__global__ __launch_bounds__(256) void k_prep(const float* __restrict__ W1, const float* __restrict__ F1,
                                              const float* __restrict__ W2, const float* __restrict__ F2,
                                              const float* __restrict__ Wp,
                                              unsigned short* __restrict__ wc1,
                                              unsigned short* __restrict__ wc2,
                                              unsigned short* __restrict__ wpb) {
    const int NW = HID_D * IN_D;          // 16384
    const int NC = 3 * NW;                // 49152
    const int NP = OUT_D * HID_D;         // 8192
    int i = blockIdx.x * 256 + threadIdx.x;
    if (i < NC) {
        wc1[i] = f2bf(i < NW ? W1[i] : F1[i - NW]);
    } else if (i < 2 * NC) {
        int j = i - NC;
        wc2[j] = f2bf(j < NW ? W2[j] : F2[j - NW]);
    } else if (i < 2 * NC + NP) {
        int j = i - 2 * NC;
        wpb[j] = f2bf(Wp[j]);
    }
}

// ---- CSR build: count, 3-kernel scan, fill ----
__global__ __launch_bounds__(256) void k_count(const int* __restrict__ dst_idx,
                                               int* __restrict__ deg, int E) {
    int e = blockIdx.x * 256 + threadIdx.x;
    if (e < E) atomicAdd(&deg[dst_idx[e]], 1);
}

__global__ __launch_bounds__(256) void k_part(const int* __restrict__ deg,
                                              int* __restrict__ part, int n) {
    int t = threadIdx.x, lane = t & 63, w = t >> 6;
    int i = blockIdx.x * 256 + t;
    int v = (i < n) ? deg[i] : 0;
    #pragma unroll
    for (int d = 32; d; d >>= 1) v += __shfl_xor(v, d);
    __shared__ int ws[4];
    if (lane == 0) ws[w] = v;
    __syncthreads();
    if (t == 0) part[blockIdx.x] = ws[0] + ws[1] + ws[2] + ws[3];
}

// single block, nb <= 256: exclusive scan of part -> base; total -> offs[n]
__global__ __launch_bounds__(256) void k_mid(const int* __restrict__ part,
                                             int* __restrict__ base,
                                             int* __restrict__ offs, int nb, int n) {
    int t = threadIdx.x, lane = t & 63, w = t >> 6;
    int v = (t < nb) ? part[t] : 0;
    int x = v;
    #pragma unroll
    for (int d = 1; d < 64; d <<= 1) {
        int y = __shfl_up(x, d);
        if (lane >= d) x += y;
    }
    __shared__ int wsum[4], woff[4];
    if (lane == 63) wsum[w] = x;
    __syncthreads();
    if (t == 0) {
        int run = 0;
        #pragma unroll
        for (int k = 0; k < 4; k++) { int s = wsum[k]; woff[k] = run; run += s; }
        offs[n] = run;
    }
    __syncthreads();
    if (t < nb) base[t] = woff[w] + x - v;
}

__global__ __launch_bounds__(256) void k_scatter(const int* __restrict__ deg,
                                                 const int* __restrict__ base,
                                                 int* __restrict__ offs,
                                                 int* __restrict__ cursor, int n) {
    int t = threadIdx.x, lane = t & 63, w = t >> 6;
    int i = blockIdx.x * 256 + t;
    int v = (i < n) ? deg[i] : 0;
    int x = v;
    #pragma unroll
    for (int d = 1; d < 64; d <<= 1) {
        int y = __shfl_up(x, d);
        if (lane >= d) x += y;
    }
    __shared__ int wsum[4], woff[4];
    if (lane == 63) wsum[w] = x;
    __syncthreads();
    if (t == 0) {
        int run = base[blockIdx.x];
        #pragma unroll
        for (int k = 0; k < 4; k++) { int s = wsum[k]; woff[k] = run; run += s; }
    }
    __syncthreads();
    int e = woff[w] + x - v;
    if (i < n) { offs[i] = e; cursor[i] = e; }
}

__global__ __launch_bounds__(256) void k_fill(const int* __restrict__ src_idx,
                                              const int* __restrict__ dst_idx,
                                              int* __restrict__ cursor,
                                              int* __restrict__ elist, int E) {
    int e = blockIdx.x * 256 + threadIdx.x;
    if (e < E) {
        int pos = atomicAdd(&cursor[dst_idx[e]], 1);
        elist[pos] = src_idx[e];
    }
}

// ---- fused GEMM + FiLM, 64 rows/block ----
__device__ __forceinline__ bf16x8 load_frag(const unsigned short* p) {
    return *(const bf16x8*)p;
}
__device__ __forceinline__ bf16x8 load_frag(const float* p) {
    float4 u = ((const float4*)p)[0];
    float4 w = ((const float4*)p)[1];
    bf16x8 r;
    r[0] = (short)f2bf(u.x); r[1] = (short)f2bf(u.y);
    r[2] = (short)f2bf(u.z); r[3] = (short)f2bf(u.w);
    r[4] = (short)f2bf(w.x); r[5] = (short)f2bf(w.y);
    r[6] = (short)f2bf(w.z); r[7] = (short)f2bf(w.w);
    return r;
}

// Wc = [W(128); Fgamma(128); Fbeta(128)] x 128 bf16 row-major.
// Block: 4 waves, 64 rows (4 row-tiles). Wave w owns m col-tiles {2w,2w+1}.
template <typename XT>
__global__ __launch_bounds__(256, 2) void k_msg(const XT* __restrict__ X,
                                                const unsigned short* __restrict__ Wc,
                                                unsigned short* __restrict__ Msg, int n) {
    const int row0 = blockIdx.x << 6;
    const int wave = threadIdx.x >> 6;
    const int lane = threadIdx.x & 63;
    const int lr = lane & 15;
    const int quad = lane >> 4;

    bf16x8 a[4][4];   // [rowtile][kstep]
    #pragma unroll
    for (int rt = 0; rt < 4; rt++) {
        int r = row0 + rt * 16 + lr;
        if (r > n - 1) r = n - 1;
        const XT* xp = X + (size_t)r * IN_D + quad * 8;
        #pragma unroll
        for (int s = 0; s < 4; s++) a[rt][s] = load_frag(xp + 32 * s);
    }

    const int t0 = wave * 2;
    const int tidx[6] = {t0, t0 + 1, t0 + 8, t0 + 9, t0 + 16, t0 + 17};
    f32x4 acc[6][4];
    #pragma unroll
    for (int u = 0; u < 6; u++)
        #pragma unroll
        for (int rt = 0; rt < 4; rt++) acc[u][rt] = (f32x4){0.f, 0.f, 0.f, 0.f};

    #pragma unroll
    for (int s = 0; s < 4; s++) {
        #pragma unroll
        for (int u = 0; u < 6; u++) {
            const bf16x8 b = *(const bf16x8*)(Wc + (size_t)(16 * tidx[u] + lr) * IN_D + quad * 8 + 32 * s);
            #pragma unroll
            for (int rt = 0; rt < 4; rt++)
                acc[u][rt] = __builtin_amdgcn_mfma_f32_16x16x32_bf16(a[rt][s], b, acc[u][rt], 0, 0, 0);
        }
    }
    // FiLM: m=acc[0..1], gamma=acc[2..3], beta=acc[4..5]; identical (row,col) slots.
    #pragma unroll
    for (int u = 0; u < 2; u++) {
        #pragma unroll
        for (int rt = 0; rt < 4; rt++) {
            #pragma unroll
            for (int r = 0; r < 4; r++) {
                int row = row0 + rt * 16 + quad * 4 + r;
                if (row < n) {
                    float v = acc[2 + u][rt][r] * acc[u][rt][r] + acc[4 + u][rt][r];
                    v = v > 0.f ? v : 0.f;
                    Msg[(size_t)row * HID_D + 16 * (t0 + u) + lr] = f2bf(v);
                }
            }
        }
    }
}

// ---- CSR aggregate + fused LayerNorm; 1 wave/node, 2 edges/iter, x2 unroll ----
__global__ __launch_bounds__(256) void k_agg_ln(const unsigned short* __restrict__ Msg,
                                                const int* __restrict__ elist,
                                                const int* __restrict__ offs,
                                                const float* __restrict__ gamma,
                                                const float* __restrict__ beta,
                                                unsigned short* __restrict__ Hout, int n) {
    int node = blockIdx.x * 4 + (threadIdx.x >> 6);
    int lane = threadIdx.x & 63;
    int half = lane >> 5;
    int l = lane & 31;
    if (node >= n) return;
    int s0 = offs[node], s1 = offs[node + 1];
    float a0 = 0.f, a1 = 0.f, a2 = 0.f, a3 = 0.f;

#define ACC4(v) { a0 += bf2f((unsigned short)((v).x & 0xffffu)); \
                  a1 += bf2f((unsigned short)((v).x >> 16));     \
                  a2 += bf2f((unsigned short)((v).y & 0xffffu)); \
                  a3 += bf2f((unsigned short)((v).y >> 16)); }

    int i = s0;
    for (; i + 4 <= s1; i += 4) {
        int iA = elist[i + half];
        int iB = elist[i + 2 + half];
        uint2 vA = *(const uint2*)(Msg + (size_t)iA * HID_D + l * 4);
        uint2 vB = *(const uint2*)(Msg + (size_t)iB * HID_D + l * 4);
        ACC4(vA);
        ACC4(vB);
    }
    for (; i + 2 <= s1; i += 2) {
        int iA = elist[i + half];
        uint2 vA = *(const uint2*)(Msg + (size_t)iA * HID_D + l * 4);
        ACC4(vA);
    }
    if (i < s1 && half == 0) {
        int iA = elist[i];
        uint2 vA = *(const uint2*)(Msg + (size_t)iA * HID_D + l * 4);
        ACC4(vA);
    }
#undef ACC4

    // fold the two half-wave partial sums
    a0 += __shfl_xor(a0, 32);
    a1 += __shfl_xor(a1, 32);
    a2 += __shfl_xor(a2, 32);
    a3 += __shfl_xor(a3, 32);

    float s = a0 + a1 + a2 + a3;
    float sq = a0 * a0 + a1 * a1 + a2 * a2 + a3 * a3;
    #pragma unroll
    for (int d = 16; d; d >>= 1) {
        s += __shfl_xor(s, d);
        sq += __shfl_xor(sq, d);
    }
    float mu = s * (1.f / 128.f);
    float var = sq * (1.f / 128.f) - mu * mu;
    float rs = rsqrtf(var + 1e-5f);
    float4 g4 = ((const float4*)gamma)[l];
    float4 b4 = ((const float4*)beta)[l];
    float y0 = (a0 - mu) * rs * g4.x + b4.x;
    float y1 = (a1 - mu) * rs * g4.y + b4.y;
    float y2 = (a2 - mu) * rs * g4.z + b4.z;
    float y3 = (a3 - mu) * rs * g4.w + b4.w;
    if (half == 0) {
        uint2 o;
        o.x = (unsigned)f2bf(y0) | ((unsigned)f2bf(y1) << 16);
        o.y = (unsigned)f2bf(y2) | ((unsigned)f2bf(y3) << 16);
        *(uint2*)(Hout + (size_t)node * HID_D + l * 4) = o;
    }
}

// ---- projection: out = sigmoid(h @ Wp^T + bp), 64 rows/block, wave w = col-tile w ----
__global__ __launch_bounds__(256) void k_proj(const unsigned short* __restrict__ H,
                                              const unsigned short* __restrict__ Wpb,
                                              const float* __restrict__ bp,
                                              float* __restrict__ out, int n) {
    const int row0 = blockIdx.x << 6;
    const int wave = threadIdx.x >> 6;
    const int lane = threadIdx.x & 63;
    const int lr = lane & 15;
    const int quad = lane >> 4;

    f32x4 acc[4];
    #pragma unroll
    for (int rt = 0; rt < 4; rt++) acc[rt] = (f32x4){0.f, 0.f, 0.f, 0.f};

    #pragma unroll
    for (int s = 0; s < 4; s++) {
        bf16x8 bv = *(const bf16x8*)(Wpb + (size_t)(16 * wave + lr) * HID_D + quad * 8 + 32 * s);
        #pragma unroll
        for (int rt = 0; rt < 4; rt++) {
            int r = row0 + rt * 16 + lr;
            if (r > n - 1) r = n - 1;
            bf16x8 av = *(const bf16x8*)(H + (size_t)r * HID_D + quad * 8 + 32 * s);
            acc[rt] = __builtin_amdgcn_mfma_f32_16x16x32_bf16(av, bv, acc[rt], 0, 0, 0);
        }
    }
    float bias = bp[16 * wave + lr];
    #pragma unroll
    for (int rt = 0; rt < 4; rt++) {
        #pragma unroll
        for (int r = 0; r < 4; r++) {
            int row = row0 + rt * 16 + quad * 4 + r;
            if (row < n) {
                float z = acc[rt][r] + bias;
                out[(size_t)row * OUT_D + 16 * wave + lr] = 1.f / (1.f + __expf(-z));
            }
        }
    }
}

extern "C" void kernel_launch(void* const* d_in, const int* in_sizes, int n_in,
                              void* d_out, int out_size, void* d_ws, size_t ws_size,
                              hipStream_t stream) {
    const float* features = (const float*)d_in[0];
    const int* src = (const int*)d_in[1];
    const int* dst = (const int*)d_in[2];
    const float* W1 = (const float*)d_in[3];
    const float* F1 = (const float*)d_in[4];
    const float* g1 = (const float*)d_in[5];
    const float* b1 = (const float*)d_in[6];
    const float* W2 = (const float*)d_in[7];
    const float* F2 = (const float*)d_in[8];
    const float* g2 = (const float*)d_in[9];
    const float* b2 = (const float*)d_in[10];
    const float* Wp = (const float*)d_in[11];
    const float* bp = (const float*)d_in[12];

    const int N = in_sizes[0] / IN_D;   // 50000
    const int E = in_sizes[1];          // 600000
    float* out = (float*)d_out;

    char* p = (char*)d_ws;
    auto alloc = [&](size_t b) -> char* {
        char* r = p;
        p += (b + 255) & ~(size_t)255;
        return r;
    };
    unsigned short* buf0 = (unsigned short*)alloc((size_t)N * HID_D * 2);
    unsigned short* buf1 = (unsigned short*)alloc((size_t)N * HID_D * 2);
    unsigned short* wc1  = (unsigned short*)alloc((size_t)3 * HID_D * IN_D * 2);
    unsigned short* wc2  = (unsigned short*)alloc((size_t)3 * HID_D * HID_D * 2);
    unsigned short* wpb  = (unsigned short*)alloc((size_t)OUT_D * HID_D * 2);
    int* deg    = (int*)alloc((size_t)N * 4);
    int* cursor = (int*)alloc((size_t)N * 4);
    int* offs   = (int*)alloc((size_t)(N + 1) * 4);
    int* elist  = (int*)alloc((size_t)E * 4);
    const int nb = (N + 255) / 256;     // 196
    int* part   = (int*)alloc((size_t)nb * 4);
    int* base   = (int*)alloc((size_t)nb * 4);

    const int eb = (E + 255) / 256;
    const int rowsb = (N + 63) / 64;    // 782

    // CSR build (graph shared by both layers)
    hipMemsetAsync(deg, 0, (size_t)N * 4, stream);
    k_count<<<eb, 256, 0, stream>>>(dst, deg, E);
    k_part<<<nb, 256, 0, stream>>>(deg, part, N);
    k_mid<<<1, 256, 0, stream>>>(part, base, offs, nb, N);
    k_scatter<<<nb, 256, 0, stream>>>(deg, base, offs, cursor, N);
    k_fill<<<eb, 256, 0, stream>>>(src, dst, cursor, elist, E);

    // weight prep (one kernel)
    const int prep_n = 2 * (3 * HID_D * IN_D) + OUT_D * HID_D;
    k_prep<<<(prep_n + 255) / 256, 256, 0, stream>>>(W1, F1, W2, F2, Wp, wc1, wc2, wpb);

    // layer 1 (reads fp32 features directly)
    k_msg<float><<<rowsb, 256, 0, stream>>>(features, wc1, buf1, N);
    k_agg_ln<<<(N + 3) / 4, 256, 0, stream>>>(buf1, elist, offs, g1, b1, buf0, N);
    // layer 2
    k_msg<unsigned short><<<rowsb, 256, 0, stream>>>(buf0, wc2, buf1, N);
    k_agg_ln<<<(N + 3) / 4, 256, 0, stream>>>(buf1, elist, offs, g2, b2, buf0, N);
    // projection + sigmoid
    k_proj<<<rowsb, 256, 0, stream>>>(buf0, wpb, bp, out, N);
}